// Round 2
// baseline (1106.632 us; speedup 1.0000x reference)
//
#include <hip/hip_runtime.h>
#include <hip/hip_bf16.h>
#include <math.h>

#define NN     100000
#define NFEATD 512
#define NHIDD  256
#define NCLS   40
#define NE     1600000
#define KHOP   10

typedef __attribute__((ext_vector_type(8))) short short8;
typedef __attribute__((ext_vector_type(4))) float floatx4;

// ---------- helpers ----------
static __device__ __forceinline__ float bf2f(unsigned int u) {
  unsigned int x = u << 16;
  float f;
  __builtin_memcpy(&f, &x, 4);
  return f;
}
static __device__ __forceinline__ unsigned short f2bf(float f) {
  unsigned int x;
  __builtin_memcpy(&x, &f, 4);
  x = (x + 0x7fffu + ((x >> 16) & 1u)) >> 16;
  return (unsigned short)x;
}
// 4 uints (8 packed bf16) -> 8 floats
static __device__ __forceinline__ void bf8_to_f(const uint4 u, float* f) {
  unsigned int a0 = u.x, a1 = u.y, a2 = u.z, a3 = u.w;
  unsigned int t;
  t = a0 << 16;          __builtin_memcpy(&f[0], &t, 4);
  t = a0 & 0xffff0000u;  __builtin_memcpy(&f[1], &t, 4);
  t = a1 << 16;          __builtin_memcpy(&f[2], &t, 4);
  t = a1 & 0xffff0000u;  __builtin_memcpy(&f[3], &t, 4);
  t = a2 << 16;          __builtin_memcpy(&f[4], &t, 4);
  t = a2 & 0xffff0000u;  __builtin_memcpy(&f[5], &t, 4);
  t = a3 << 16;          __builtin_memcpy(&f[6], &t, 4);
  t = a3 & 0xffff0000u;  __builtin_memcpy(&f[7], &t, 4);
}

// ---------- W1 [512][256] fp32 -> Wt2 staged layout: [k/8][256 hid][8 k] bf16 ----------
// This makes the fused kernel's Wt staging loads perfectly coalesced.
__global__ __launch_bounds__(256) void wt_kernel(const float* __restrict__ W1,
                                                 unsigned short* __restrict__ Wt2) {
  int i = blockIdx.x * 256 + threadIdx.x;  // over 512*256, W1[k][n]
  int k = i >> 8;
  int n = i & 255;
  Wt2[(k >> 3) * 2048 + n * 8 + (k & 7)] = f2bf(W1[i]);
}

// ---------- Fused MLP: hb = (relu(x @ W1 + b1)) @ W2 + b2, bf16 out ----------
// Swapped MFMA operands: A = W1^T (hidden-major), B = x rows.
// Wave w owns x-rows [r0 + w*16, +16) x all 256 hidden.
// C layout: lane holds h[hidden = i*16 + quad*4 + reg][row = r0 + w*16 + (lane&15)]
// -> second GEMM (h @ W2) is lane-local FMA over 64 hidden + 2-step quad reduce.
// K-loop: BK=32, 16 steps, double-buffered LDS, depth-2 register prefetch,
// one barrier per step. LDS layouts [q][row][8] are ds_read conflict-free.
__global__ __launch_bounds__(256) void mlp_fused_kernel(
    const float* __restrict__ x, const unsigned short* __restrict__ Wt2,
    const float* __restrict__ b1, const float* __restrict__ W2,
    const float* __restrict__ b2, unsigned short* __restrict__ hb) {
  // staging: buf p at smem + p*20480: xs 4KB [4][64][8] bf16, wts 16KB [4][256][8] bf16
  // epilogue overlay: W2s fp32 [256][44] = 45056 B (pad 44 breaks 4-quad bank clash)
  __shared__ __align__(16) char smem[45056];
  __shared__ float b1s[256];
  __shared__ float b2s[64];
  const int tid = threadIdx.x;
  const int lane = tid & 63;
  const int w = tid >> 6;
  const int m = lane & 15;
  const int quad = lane >> 4;
  const int r0 = blockIdx.x * 64;

  b1s[tid] = b1[tid];

  // x staging: thread t stages chunk (q = t&3, row = t>>2) -> 128B-contig runs
  const int sx_row = tid >> 2;
  const int sx_q = tid & 3;
  int gxrow = r0 + sx_row;
  if (gxrow >= NN) gxrow = NN - 1;
  const float* xsrc = x + (size_t)gxrow * NFEATD + sx_q * 8;
  const int sx_chunk = sx_q * 64 + sx_row;
  // Wt staging: call c stages chunk (q = c, hid = tid) -> fully coalesced
  const unsigned short* wsrc = Wt2 + tid * 8;

  unsigned short* xs0 = (unsigned short*)(smem);
  unsigned short* wts0 = (unsigned short*)(smem + 4096);
  unsigned short* xs1 = (unsigned short*)(smem + 20480);
  unsigned short* wts1 = (unsigned short*)(smem + 20480 + 4096);

  floatx4 acc[16];
#pragma unroll
  for (int i = 0; i < 16; ++i) acc[i] = (floatx4){0.f, 0.f, 0.f, 0.f};

  // depth-2 register prefetch buffers (statically indexed after full unroll)
  float4 xr[2][2];
  uint4 wr_[2][4];
#pragma unroll
  for (int t = 0; t < 2; ++t) {
    const int kt = t * 32;
    xr[t][0] = *(const float4*)(xsrc + kt);
    xr[t][1] = *(const float4*)(xsrc + kt + 4);
#pragma unroll
    for (int c = 0; c < 4; ++c)
      wr_[t][c] = *(const uint4*)(wsrc + ((kt >> 3) + c) * 2048);
  }

#pragma unroll
  for (int t = 0; t < 16; ++t) {
    const int p = t & 1;
    unsigned short* xsp = p ? xs1 : xs0;
    unsigned short* wtsp = p ? wts1 : wts0;
    // ds_write step-t tile (regs loaded 2 iterations ago)
    {
      short8 xo;
      xo[0] = (short)f2bf(xr[p][0].x);
      xo[1] = (short)f2bf(xr[p][0].y);
      xo[2] = (short)f2bf(xr[p][0].z);
      xo[3] = (short)f2bf(xr[p][0].w);
      xo[4] = (short)f2bf(xr[p][1].x);
      xo[5] = (short)f2bf(xr[p][1].y);
      xo[6] = (short)f2bf(xr[p][1].z);
      xo[7] = (short)f2bf(xr[p][1].w);
      *(short8*)(xsp + sx_chunk * 8) = xo;
#pragma unroll
      for (int c = 0; c < 4; ++c)
        *(uint4*)(wtsp + (c * 256 + tid) * 8) = wr_[p][c];
    }
    // issue loads for step t+2 (~2 barrier intervals of latency cover)
    if (t + 2 < 16) {
      const int kt = (t + 2) * 32;
      xr[p][0] = *(const float4*)(xsrc + kt);
      xr[p][1] = *(const float4*)(xsrc + kt + 4);
#pragma unroll
      for (int c = 0; c < 4; ++c)
        wr_[p][c] = *(const uint4*)(wsrc + ((kt >> 3) + c) * 2048);
    }
    __syncthreads();
    // read frags + MFMA
    short8 xf = *(const short8*)(xsp + (quad * 64 + w * 16 + m) * 8);
#pragma unroll
    for (int i = 0; i < 16; ++i) {
      short8 af = *(const short8*)(wtsp + (quad * 256 + i * 16 + m) * 8);
      acc[i] = __builtin_amdgcn_mfma_f32_16x16x32_bf16(af, xf, acc[i], 0, 0, 0);
    }
  }

  // ---- fused second GEMM: out[row][cls] = relu(h+b1) @ W2 + b2 ----
  __syncthreads();  // all waves done reading staging buffers
  {
    // stage W2 fp32 into overlay with padded stride 44
    float* W2s = (float*)smem;
    const float* wrow = W2 + tid * 40;
    float4 tmp[10];
#pragma unroll
    for (int i2 = 0; i2 < 10; ++i2) tmp[i2] = *(const float4*)(wrow + i2 * 4);
#pragma unroll
    for (int i2 = 0; i2 < 10; ++i2) *(float4*)&W2s[tid * 44 + i2 * 4] = tmp[i2];
    if (tid < NCLS) b2s[tid] = b2[tid];
  }
  __syncthreads();

  // bias + relu in place (lane's hidden = i*16 + quad*4 + r)
#pragma unroll
  for (int i = 0; i < 16; ++i)
#pragma unroll
    for (int r = 0; r < 4; ++r)
      acc[i][r] = fmaxf(acc[i][r] + b1s[i * 16 + quad * 4 + r], 0.f);

  const float* W2s = (const float*)smem;
  const int grow = r0 + w * 16 + m;
  for (int c = 0; c < 5; ++c) {
    const int c0 = c * 8;
    float pa[8];
#pragma unroll
    for (int j = 0; j < 8; ++j) pa[j] = 0.f;
#pragma unroll
    for (int i = 0; i < 16; ++i) {
#pragma unroll
      for (int r = 0; r < 4; ++r) {
        const int hid = i * 16 + quad * 4 + r;
        const float hv = acc[i][r];
        const float* wv = W2s + hid * 44 + c0;
        float4 wa = *(const float4*)wv;
        float4 wb = *(const float4*)(wv + 4);
        pa[0] = fmaf(hv, wa.x, pa[0]);
        pa[1] = fmaf(hv, wa.y, pa[1]);
        pa[2] = fmaf(hv, wa.z, pa[2]);
        pa[3] = fmaf(hv, wa.w, pa[3]);
        pa[4] = fmaf(hv, wb.x, pa[4]);
        pa[5] = fmaf(hv, wb.y, pa[5]);
        pa[6] = fmaf(hv, wb.z, pa[6]);
        pa[7] = fmaf(hv, wb.w, pa[7]);
      }
    }
    // reduce across the 4 quads (hidden partition)
#pragma unroll
    for (int j = 0; j < 8; ++j) {
      pa[j] += __shfl_xor(pa[j], 16);
      pa[j] += __shfl_xor(pa[j], 32);
    }
    if (quad == 0 && grow < NN) {
      unsigned int u[4];
#pragma unroll
      for (int jj = 0; jj < 4; ++jj) {
        unsigned int lo = f2bf(pa[2 * jj] + b2s[c0 + 2 * jj]);
        unsigned int hi = f2bf(pa[2 * jj + 1] + b2s[c0 + 2 * jj + 1]);
        u[jj] = lo | (hi << 16);
      }
      uint4 o;
      o.x = u[0];
      o.y = u[1];
      o.z = u[2];
      o.w = u[3];
      *(uint4*)(hb + (size_t)grow * NCLS + c0) = o;
    }
  }
}

// ---------- CSR build (degree-sorted row order, block-aggregated sort) ----------
__global__ __launch_bounds__(256) void zero_kernel(int* __restrict__ p, int n) {
  int i = blockIdx.x * 256 + threadIdx.x;
  if (i < n) p[i] = 0;
}
__global__ __launch_bounds__(256) void count_kernel(const int* __restrict__ edst,
                                                    int* __restrict__ counts) {
  int e = blockIdx.x * 256 + threadIdx.x;
  if (e < NE) atomicAdd(&counts[edst[e]], 1);
}
// block-local LDS histogram, one global atomic per (block, bin)
__global__ __launch_bounds__(256) void hist_kernel(const int* __restrict__ counts,
                                                   int* __restrict__ binoff) {
  __shared__ int lhist[64];
  int tid = threadIdx.x;
  if (tid < 64) lhist[tid] = 0;
  __syncthreads();
  int r = blockIdx.x * 256 + tid;
  if (r < NN) {
    int d = counts[r];
    if (d > 63) d = 63;
    atomicAdd(&lhist[d], 1);
  }
  __syncthreads();
  if (tid < 64) {
    int c = lhist[tid];
    if (c) atomicAdd(&binoff[tid], c);
  }
}
__global__ __launch_bounds__(64) void binscan_kernel(int* __restrict__ binoff) {
  __shared__ int s[64];
  int t = threadIdx.x;
  s[t] = binoff[t];
  __syncthreads();
  if (t == 0) {
    int run = 0;
    for (int i = 0; i < 64; ++i) {
      int c = s[i];
      s[i] = run;
      run += c;
    }
  }
  __syncthreads();
  binoff[t] = s[t];
}
// local rank via LDS atomics; block reserves a bin range with ONE global atomic
__global__ __launch_bounds__(256) void scatter_rows_kernel(
    const int* __restrict__ counts, int* __restrict__ binoff,
    int* __restrict__ perm, int* __restrict__ spos) {
  __shared__ int lhist[64];
  __shared__ int lbase[64];
  int tid = threadIdx.x;
  if (tid < 64) lhist[tid] = 0;
  __syncthreads();
  int r = blockIdx.x * 256 + tid;
  int d = 0, lrank = 0;
  bool valid = (r < NN);
  if (valid) {
    d = counts[r];
    if (d > 63) d = 63;
    lrank = atomicAdd(&lhist[d], 1);
  }
  __syncthreads();
  if (tid < 64) {
    int c = lhist[tid];
    lbase[tid] = c ? atomicAdd(&binoff[tid], c) : 0;
  }
  __syncthreads();
  if (valid) {
    int pos = lbase[d] + lrank;
    perm[pos] = r;
    spos[r] = pos;
  }
}
__global__ __launch_bounds__(256) void scan_blocks_kernel(
    const int* __restrict__ counts, const int* __restrict__ perm,
    int* __restrict__ srs, int* __restrict__ bsum) {
  __shared__ int s[256];
  int gid = blockIdx.x * 256 + threadIdx.x;
  int v = (gid < NN) ? counts[perm[gid]] : 0;
  s[threadIdx.x] = v;
  __syncthreads();
  for (int off = 1; off < 256; off <<= 1) {
    int t = (threadIdx.x >= off) ? s[threadIdx.x - off] : 0;
    __syncthreads();
    s[threadIdx.x] += t;
    __syncthreads();
  }
  if (gid < NN) srs[gid + 1] = s[threadIdx.x];
  if (threadIdx.x == 255) bsum[blockIdx.x] = s[255];
}
#define NB 391
__global__ __launch_bounds__(512) void scan_sums_kernel(int* __restrict__ bsum) {
  __shared__ int s[512];
  int tid = threadIdx.x;
  int v = (tid < NB) ? bsum[tid] : 0;
  s[tid] = v;
  __syncthreads();
  for (int off = 1; off < 512; off <<= 1) {
    int t = (tid >= off) ? s[tid - off] : 0;
    __syncthreads();
    s[tid] += t;
    __syncthreads();
  }
  if (tid < NB) bsum[tid] = (tid == 0) ? 0 : s[tid - 1];  // exclusive
}
__global__ __launch_bounds__(256) void add_off_kernel(int* __restrict__ srs,
                                                      const int* __restrict__ bsum) {
  int gid = blockIdx.x * 256 + threadIdx.x;
  if (gid < NN) srs[gid + 1] += bsum[blockIdx.x];
  if (gid == 0) srs[0] = 0;
}
__global__ __launch_bounds__(256) void scatter_kernel(
    const int* __restrict__ esrc, const int* __restrict__ edst,
    const float* __restrict__ eval, const int* __restrict__ srs,
    const int* __restrict__ spos, int* __restrict__ cursor,
    int2* __restrict__ csr_pair) {
  int e = blockIdx.x * 256 + threadIdx.x;
  if (e < NE) {
    int p = spos[edst[e]];
    int idx = srs[p] + atomicAdd(&cursor[p], 1);
    csr_pair[idx] = make_int2(esrc[e], __float_as_int(eval[e]));
  }
}

// ---------- propagation: zo[r] = 0.9 * (A z)[r] + 0.1 * h[r], bf16 ----------
__global__ __launch_bounds__(256) void prop_kernel(
    const int* __restrict__ srs, const int* __restrict__ perm,
    const int2* __restrict__ csr_pair, const unsigned short* __restrict__ zi,
    const unsigned short* __restrict__ hb, unsigned short* __restrict__ zo) {
  int t = blockIdx.x * 256 + threadIdx.x;
  if (t >= NN * 5) return;
  unsigned int p = (unsigned int)t / 5u;
  int cg8 = (t - (int)p * 5) * 8;  // col offset in bf16 elems
  int e0 = srs[p], e1 = srs[p + 1];
  int r = perm[p];
  float acc[8];
#pragma unroll
  for (int j = 0; j < 8; ++j) acc[j] = 0.f;

  int e = e0;
  for (; e + 8 <= e1; e += 8) {
    int2 pr[8];
#pragma unroll
    for (int q = 0; q < 8; ++q) pr[q] = csr_pair[e + q];
    uint4 g[8];
#pragma unroll
    for (int q = 0; q < 8; ++q)
      g[q] = *(const uint4*)(zi + pr[q].x * NCLS + cg8);
#pragma unroll
    for (int q = 0; q < 8; ++q) {
      float zf[8];
      bf8_to_f(g[q], zf);
      float v = __int_as_float(pr[q].y);
#pragma unroll
      for (int j = 0; j < 8; ++j) acc[j] = fmaf(v, zf[j], acc[j]);
    }
  }
  for (; e < e1; ++e) {
    int2 pr = csr_pair[e];
    uint4 g = *(const uint4*)(zi + pr.x * NCLS + cg8);
    float zf[8];
    bf8_to_f(g, zf);
    float v = __int_as_float(pr.y);
#pragma unroll
    for (int j = 0; j < 8; ++j) acc[j] = fmaf(v, zf[j], acc[j]);
  }

  uint4 hu = *(const uint4*)(hb + r * NCLS + cg8);
  float hf[8];
  bf8_to_f(hu, hf);
  uint4 o;
  unsigned int wv[4];
#pragma unroll
  for (int i = 0; i < 4; ++i) {
    unsigned int lo = f2bf(0.9f * acc[2 * i] + 0.1f * hf[2 * i]);
    unsigned int hi = f2bf(0.9f * acc[2 * i + 1] + 0.1f * hf[2 * i + 1]);
    wv[i] = lo | (hi << 16);
  }
  o.x = wv[0];
  o.y = wv[1];
  o.z = wv[2];
  o.w = wv[3];
  *(uint4*)(zo + r * NCLS + cg8) = o;
}

// ---------- log_softmax: bf16 z -> fp32 out ----------
__global__ __launch_bounds__(256) void lsm_kernel(const unsigned short* __restrict__ zf,
                                                  float* __restrict__ out) {
  int r = blockIdx.x * 256 + threadIdx.x;
  if (r >= NN) return;
  float v[NCLS];
#pragma unroll
  for (int q = 0; q < 5; ++q) {
    uint4 u = *(const uint4*)(zf + r * NCLS + q * 8);
    bf8_to_f(u, v + q * 8);
  }
  float m = v[0];
#pragma unroll
  for (int i = 1; i < NCLS; ++i) m = fmaxf(m, v[i]);
  float ssum = 0.f;
#pragma unroll
  for (int i = 0; i < NCLS; ++i) ssum += expf(v[i] - m);
  float lse = m + logf(ssum);
#pragma unroll
  for (int q = 0; q < 10; ++q) {
    float4 o;
    o.x = v[q * 4 + 0] - lse;
    o.y = v[q * 4 + 1] - lse;
    o.z = v[q * 4 + 2] - lse;
    o.w = v[q * 4 + 3] - lse;
    *(float4*)(out + r * NCLS + q * 4) = o;
  }
}

extern "C" void kernel_launch(void* const* d_in, const int* in_sizes, int n_in,
                              void* d_out, int out_size, void* d_ws, size_t ws_size,
                              hipStream_t stream) {
  const float* x = (const float*)d_in[0];
  const int* esrc = (const int*)d_in[1];
  const int* edst = (const int*)d_in[2];
  const float* eval = (const float*)d_in[3];
  const float* W1 = (const float*)d_in[4];
  const float* b1 = (const float*)d_in[5];
  const float* W2 = (const float*)d_in[6];
  const float* b2 = (const float*)d_in[7];
  float* out = (float*)d_out;
  char* ws = (char*)d_ws;

  // workspace layout (bytes)
  unsigned short* hb = (unsigned short*)(ws + 0);         // 8,000,000 (h bf16)
  unsigned short* zB0 = (unsigned short*)(ws + 8000000);  // 8,000,000
  unsigned short* zB1 = (unsigned short*)(ws + 16000000); // 8,000,000
  unsigned short* Wt2 = (unsigned short*)(ws + 24000000); // 262,144
  int* counts = (int*)(ws + 75600000);                    // 400,000
  int* cursor = (int*)(ws + 76000000);                    // 400,000
  int* srs = (int*)(ws + 76400000);                       // 400,004 (+pad)
  int* bsum = (int*)(ws + 76800064);                      // 2,048
  int* binoff = (int*)(ws + 76802112);                    // 256
  int* perm = (int*)(ws + 76802624);                      // 400,000
  int* spos = (int*)(ws + 77202624);                      // 400,000
  int2* csr_pair = (int2*)(ws + 77602624);                // 12,800,000

  // zero counts + cursor (adjacent), and binoff
  zero_kernel<<<(2 * NN + 255) / 256, 256, 0, stream>>>(counts, 2 * NN);
  zero_kernel<<<1, 256, 0, stream>>>(binoff, 64);

  // fused MLP: x @ W1 -> relu -> @ W2 -> hb (no h1 round-trip)
  wt_kernel<<<(NFEATD * NHIDD) / 256, 256, 0, stream>>>(W1, Wt2);
  mlp_fused_kernel<<<(NN + 63) / 64, 256, 0, stream>>>(x, Wt2, b1, W2, b2, hb);

  // CSR build in degree-sorted row space
  count_kernel<<<(NE + 255) / 256, 256, 0, stream>>>(edst, counts);
  hist_kernel<<<(NN + 255) / 256, 256, 0, stream>>>(counts, binoff);
  binscan_kernel<<<1, 64, 0, stream>>>(binoff);
  scatter_rows_kernel<<<(NN + 255) / 256, 256, 0, stream>>>(counts, binoff, perm, spos);
  scan_blocks_kernel<<<NB, 256, 0, stream>>>(counts, perm, srs, bsum);
  scan_sums_kernel<<<1, 512, 0, stream>>>(bsum);
  add_off_kernel<<<NB, 256, 0, stream>>>(srs, bsum);
  scatter_kernel<<<(NE + 255) / 256, 256, 0, stream>>>(esrc, edst, eval, srs, spos,
                                                       cursor, csr_pair);

  // propagation: hb -> zB0 -> zB1 -> ... (10 hops, ends in zB1)
  const unsigned short* zin = hb;
  unsigned short* zout = zB0;
  for (int i = 0; i < KHOP; ++i) {
    prop_kernel<<<(NN * 5 + 255) / 256, 256, 0, stream>>>(srs, perm, csr_pair,
                                                          zin, hb, zout);
    if (i == 0) {
      zin = zB0;
      zout = zB1;
    } else {
      unsigned short* t = (unsigned short*)zin;
      zin = zout;
      zout = t;
    }
  }

  // log_softmax from bf16 z (hop 10 output = zB1) -> fp32 out
  lsm_kernel<<<(NN + 255) / 256, 256, 0, stream>>>(zB1, out);
}

// Round 3
// 1049.083 us; speedup vs baseline: 1.0549x; 1.0549x over previous
//
#include <hip/hip_runtime.h>
#include <hip/hip_bf16.h>
#include <math.h>

#define NN     100000
#define NFEATD 512
#define NHIDD  256
#define NCLS   40
#define NE     1600000
#define KHOP   10

typedef __attribute__((ext_vector_type(8))) short short8;
typedef __attribute__((ext_vector_type(4))) float floatx4;

// ---------- helpers ----------
static __device__ __forceinline__ float bf2f(unsigned int u) {
  unsigned int x = u << 16;
  float f;
  __builtin_memcpy(&f, &x, 4);
  return f;
}
static __device__ __forceinline__ unsigned short f2bf(float f) {
  unsigned int x;
  __builtin_memcpy(&x, &f, 4);
  x = (x + 0x7fffu + ((x >> 16) & 1u)) >> 16;
  return (unsigned short)x;
}
// 4 uints (8 packed bf16) -> 8 floats
static __device__ __forceinline__ void bf8_to_f(const uint4 u, float* f) {
  unsigned int a0 = u.x, a1 = u.y, a2 = u.z, a3 = u.w;
  unsigned int t;
  t = a0 << 16;          __builtin_memcpy(&f[0], &t, 4);
  t = a0 & 0xffff0000u;  __builtin_memcpy(&f[1], &t, 4);
  t = a1 << 16;          __builtin_memcpy(&f[2], &t, 4);
  t = a1 & 0xffff0000u;  __builtin_memcpy(&f[3], &t, 4);
  t = a2 << 16;          __builtin_memcpy(&f[4], &t, 4);
  t = a2 & 0xffff0000u;  __builtin_memcpy(&f[5], &t, 4);
  t = a3 << 16;          __builtin_memcpy(&f[6], &t, 4);
  t = a3 & 0xffff0000u;  __builtin_memcpy(&f[7], &t, 4);
}

// ---------- W1 [512][256] fp32 -> Wt [256][512] bf16 ----------
__global__ __launch_bounds__(256) void wt_kernel(const float* __restrict__ W1,
                                                 unsigned short* __restrict__ Wt) {
  int i = blockIdx.x * 256 + threadIdx.x;  // over 512*256
  int k = i >> 8;
  int n = i & 255;
  Wt[n * 512 + k] = f2bf(W1[i]);
}

// ---------- GEMM1: h1 = relu(x @ W1 + b1) ----------
// Round-0 proven tile/frag/C-layout, restructured:
//  - double-buffered LDS: ONE barrier per 32-K-step (round-0 had two)
//  - raw s_barrier + asm lgkmcnt(0) only => global prefetch loads stay in
//    flight across barriers (no __syncthreads vmcnt(0) drain)
//  - depth-2 register prefetch with STATIC reg-set names (aA/aB), no
//    runtime-indexed arrays (no scratch)
//  - LDS-staged epilogue: full 256B-line h1 writes (round-1 proven, WRITE 2x fix)
__global__ __launch_bounds__(256) void gemm1_mfma_kernel(
    const float* __restrict__ x, const unsigned short* __restrict__ Wt,
    const float* __restrict__ b1, unsigned short* __restrict__ h1) {
  __shared__ __align__(16) unsigned short smem_u[20480];  // 40KB: 2x(As+Bs); hs overlays
  unsigned short* As0 = smem_u;           // [128][40]
  unsigned short* Bs0 = smem_u + 5120;    // [128][40]
  unsigned short* As1 = smem_u + 10240;
  unsigned short* Bs1 = smem_u + 15360;
  unsigned short* hs = smem_u;            // [128][128] epilogue overlay (32KB)
  const int tid = threadIdx.x;
  const int lane = tid & 63;
  const int wave = tid >> 6;
  const int wr = wave >> 1, wc = wave & 1;
  const int m = lane & 15, quad = lane >> 4;
  const int c0 = blockIdx.x * 128;  // col block (0 or 128)
  const int r0 = blockIdx.y * 128;  // row block

  const int arow = tid >> 3;  // 0..31 (+rep*32)
  const int akq = tid & 7;    // float4 index within 32-k tile
  const int brow = tid >> 2;  // 0..63 (+rep*64)
  const int bkq = tid & 3;    // 16B chunk within 32-k tile

  floatx4 acc[4][4];
#pragma unroll
  for (int i = 0; i < 4; ++i)
#pragma unroll
    for (int j = 0; j < 4; ++j) acc[i][j] = (floatx4){0.f, 0.f, 0.f, 0.f};

  // source pointers (rows clamped; OOB rows produce garbage h-rows that are
  // masked at the global store)
  const float* asrc[4];
#pragma unroll
  for (int rep = 0; rep < 4; ++rep) {
    int grow = r0 + arow + rep * 32;
    asrc[rep] = x + (size_t)(grow < NN ? grow : 0) * NFEATD + akq * 4;
  }
  const unsigned short* bsrc[2];
#pragma unroll
  for (int rep = 0; rep < 2; ++rep)
    bsrc[rep] = Wt + (size_t)(c0 + brow + rep * 64) * NFEATD + bkq * 8;

#define LOAD_A(dst, koff)                                        \
  {                                                              \
    _Pragma("unroll") for (int rep = 0; rep < 4; ++rep)          \
        dst[rep] = *(const float4*)(asrc[rep] + (koff));         \
  }
#define LOAD_B(dst, koff)                                        \
  {                                                              \
    _Pragma("unroll") for (int rep = 0; rep < 2; ++rep)          \
        dst[rep] = *(const uint4*)(bsrc[rep] + (koff));          \
  }
#define STAGE(Ad, Bd, aregs, bregs)                              \
  {                                                              \
    _Pragma("unroll") for (int rep = 0; rep < 4; ++rep) {        \
      ushort4 o;                                                 \
      o.x = f2bf(aregs[rep].x);                                  \
      o.y = f2bf(aregs[rep].y);                                  \
      o.z = f2bf(aregs[rep].z);                                  \
      o.w = f2bf(aregs[rep].w);                                  \
      *(ushort4*)&Ad[(arow + rep * 32) * 40 + akq * 4] = o;      \
    }                                                            \
    _Pragma("unroll") for (int rep = 0; rep < 2; ++rep)          \
        *(uint4*)&Bd[(brow + rep * 64) * 40 + bkq * 8] = bregs[rep]; \
  }
#define COMPUTE(Asb, Bsb)                                        \
  {                                                              \
    short8 af[4], bfr[4];                                        \
    _Pragma("unroll") for (int i = 0; i < 4; ++i)                \
        af[i] = *(const short8*)&Asb[(wr * 64 + i * 16 + m) * 40 + quad * 8]; \
    _Pragma("unroll") for (int j = 0; j < 4; ++j)                \
        bfr[j] = *(const short8*)&Bsb[(wc * 64 + j * 16 + m) * 40 + quad * 8]; \
    _Pragma("unroll") for (int i = 0; i < 4; ++i)                \
        _Pragma("unroll") for (int j = 0; j < 4; ++j)            \
            acc[i][j] = __builtin_amdgcn_mfma_f32_16x16x32_bf16( \
                af[i], bfr[j], acc[i][j], 0, 0, 0);              \
  }
#define BAR()                                                    \
  {                                                              \
    asm volatile("s_waitcnt lgkmcnt(0)" ::: "memory");           \
    __builtin_amdgcn_s_barrier();                                \
  }

  float4 aA[4], aB[4];
  uint4 bA[2], bB[2];
  // prologue: tile0 -> regs -> buf0; tile1 -> regs(B); refill regs(A) with tile2
  LOAD_A(aA, 0); LOAD_B(bA, 0);
  LOAD_A(aB, 32); LOAD_B(bB, 32);
  STAGE(As0, Bs0, aA, bA);
  BAR();
  LOAD_A(aA, 64); LOAD_B(bA, 64);

  // 8 iterations x 2 tiles; tile s computed from buf[s&1]; stage runs 1 tile
  // ahead, register loads run 2-3 tiles ahead (in flight across barriers).
#pragma unroll 1
  for (int t = 0; t < 8; ++t) {
    const int kt = t * 64;
    // ---- substep 0: compute tile 2t (buf0); stage tile 2t+1 (aB->buf1) ----
    STAGE(As1, Bs1, aB, bB);
    if (t < 7) { LOAD_A(aB, kt + 96); LOAD_B(bB, kt + 96); }  // tile 2t+3
    COMPUTE(As0, Bs0);
    BAR();
    // ---- substep 1: compute tile 2t+1 (buf1); stage tile 2t+2 (aA->buf0) ----
    if (t < 7) {
      STAGE(As0, Bs0, aA, bA);
      if (t < 6) { LOAD_A(aA, kt + 128); LOAD_B(bA, kt + 128); }  // tile 2t+4
    }
    COMPUTE(As1, Bs1);
    BAR();
  }

  // epilogue: bias+relu -> bf16 tile in LDS -> full-line coalesced h1 write
  float bias[4];
#pragma unroll
  for (int j = 0; j < 4; ++j) bias[j] = b1[c0 + wc * 64 + j * 16 + m];
#pragma unroll
  for (int i = 0; i < 4; ++i)
#pragma unroll
    for (int r = 0; r < 4; ++r) {
      int rl = wr * 64 + i * 16 + quad * 4 + r;
#pragma unroll
      for (int j = 0; j < 4; ++j)
        hs[rl * 128 + wc * 64 + j * 16 + m] =
            f2bf(fmaxf(acc[i][j][r] + bias[j], 0.f));
    }
  BAR();
#pragma unroll
  for (int rep = 0; rep < 8; ++rep) {
    int idx = rep * 256 + tid;  // 16B chunk id; 2048 chunks = 32KB
    int row = idx >> 4;         // 16 chunks per 256B tile row
    int grow = r0 + row;
    if (grow < NN) {
      uint4 v = *(const uint4*)&hs[idx * 8];
      *(uint4*)(h1 + (size_t)grow * NHIDD + c0 + (idx & 15) * 8) = v;
    }
  }
#undef LOAD_A
#undef LOAD_B
#undef STAGE
#undef COMPUTE
#undef BAR
}

// ---------- GEMM2: hb(bf16) = h1(bf16) @ W2 + b2 ----------
// v2: float4 W2 staging; float2 W2 inner reads (11 vs 21 LDS ops per 2-k).
// Accumulation order identical to round-0 (bitwise-same result).
__global__ __launch_bounds__(256) void gemm2_kernel(
    const unsigned short* __restrict__ h1, const float* __restrict__ W2,
    const float* __restrict__ b2, unsigned short* __restrict__ hb) {
  __shared__ float w2s[NHIDD * NCLS];  // 40 KB
  __shared__ float b2s[NCLS];
  __shared__ unsigned short h1s[64 * 264];  // padded stride
  const int tid = threadIdx.x;
  const int r0 = blockIdx.x * 64;
#pragma unroll
  for (int i = 0; i < 10; ++i)
    ((float4*)w2s)[tid + i * 256] = ((const float4*)W2)[tid + i * 256];
  if (tid < NCLS) b2s[tid] = b2[tid];
#pragma unroll
  for (int q = 0; q < 8; ++q) {
    int l = tid + q * 256;
    int lr = l >> 5;
    int lc = (l & 31) << 3;
    int row = r0 + lr;
    uint4 v = make_uint4(0, 0, 0, 0);
    if (row < NN) v = *(const uint4*)(h1 + (size_t)row * NHIDD + lc);
    *(uint4*)&h1s[lr * 264 + lc] = v;
  }
  __syncthreads();
  const int lr = tid >> 2;
  const int cq = (tid & 3) * 10;
  float acc[10];
#pragma unroll
  for (int j = 0; j < 10; ++j) acc[j] = 0.f;
#pragma unroll 4
  for (int k = 0; k < NHIDD; k += 2) {
    unsigned int hp = *(const unsigned int*)&h1s[lr * 264 + k];
    float a0 = bf2f(hp & 0xffffu);
    float a1 = bf2f(hp >> 16);
    const float* w0 = &w2s[k * NCLS + cq];
    const float* w1 = &w2s[(k + 1) * NCLS + cq];
#pragma unroll
    for (int j2 = 0; j2 < 5; ++j2) {
      float2 wa = *(const float2*)(w0 + 2 * j2);
      float2 wb = *(const float2*)(w1 + 2 * j2);
      acc[2 * j2] = fmaf(a1, wb.x, fmaf(a0, wa.x, acc[2 * j2]));
      acc[2 * j2 + 1] = fmaf(a1, wb.y, fmaf(a0, wa.y, acc[2 * j2 + 1]));
    }
  }
  int row = r0 + lr;
  if (row < NN) {
#pragma unroll
    for (int jj = 0; jj < 5; ++jj) {
      unsigned int u = (unsigned int)f2bf(acc[2 * jj] + b2s[cq + 2 * jj]) |
                       ((unsigned int)f2bf(acc[2 * jj + 1] + b2s[cq + 2 * jj + 1]) << 16);
      *(unsigned int*)&hb[(size_t)row * NCLS + cq + 2 * jj] = u;
    }
  }
}

// ---------- CSR build (degree-sorted row order, block-aggregated sort) ----------
__global__ __launch_bounds__(256) void zero_kernel(int* __restrict__ p, int n) {
  int i = blockIdx.x * 256 + threadIdx.x;
  if (i < n) p[i] = 0;
}
__global__ __launch_bounds__(256) void count_kernel(const int* __restrict__ edst,
                                                    int* __restrict__ counts) {
  int e = blockIdx.x * 256 + threadIdx.x;
  if (e < NE) atomicAdd(&counts[edst[e]], 1);
}
// block-local LDS histogram, one global atomic per (block, bin)
__global__ __launch_bounds__(256) void hist_kernel(const int* __restrict__ counts,
                                                   int* __restrict__ binoff) {
  __shared__ int lhist[64];
  int tid = threadIdx.x;
  if (tid < 64) lhist[tid] = 0;
  __syncthreads();
  int r = blockIdx.x * 256 + tid;
  if (r < NN) {
    int d = counts[r];
    if (d > 63) d = 63;
    atomicAdd(&lhist[d], 1);
  }
  __syncthreads();
  if (tid < 64) {
    int c = lhist[tid];
    if (c) atomicAdd(&binoff[tid], c);
  }
}
__global__ __launch_bounds__(64) void binscan_kernel(int* __restrict__ binoff) {
  __shared__ int s[64];
  int t = threadIdx.x;
  s[t] = binoff[t];
  __syncthreads();
  if (t == 0) {
    int run = 0;
    for (int i = 0; i < 64; ++i) {
      int c = s[i];
      s[i] = run;
      run += c;
    }
  }
  __syncthreads();
  binoff[t] = s[t];
}
// local rank via LDS atomics; block reserves a bin range with ONE global atomic
__global__ __launch_bounds__(256) void scatter_rows_kernel(
    const int* __restrict__ counts, int* __restrict__ binoff,
    int* __restrict__ perm, int* __restrict__ spos) {
  __shared__ int lhist[64];
  __shared__ int lbase[64];
  int tid = threadIdx.x;
  if (tid < 64) lhist[tid] = 0;
  __syncthreads();
  int r = blockIdx.x * 256 + tid;
  int d = 0, lrank = 0;
  bool valid = (r < NN);
  if (valid) {
    d = counts[r];
    if (d > 63) d = 63;
    lrank = atomicAdd(&lhist[d], 1);
  }
  __syncthreads();
  if (tid < 64) {
    int c = lhist[tid];
    lbase[tid] = c ? atomicAdd(&binoff[tid], c) : 0;
  }
  __syncthreads();
  if (valid) {
    int pos = lbase[d] + lrank;
    perm[pos] = r;
    spos[r] = pos;
  }
}
__global__ __launch_bounds__(256) void scan_blocks_kernel(
    const int* __restrict__ counts, const int* __restrict__ perm,
    int* __restrict__ srs, int* __restrict__ bsum) {
  __shared__ int s[256];
  int gid = blockIdx.x * 256 + threadIdx.x;
  int v = (gid < NN) ? counts[perm[gid]] : 0;
  s[threadIdx.x] = v;
  __syncthreads();
  for (int off = 1; off < 256; off <<= 1) {
    int t = (threadIdx.x >= off) ? s[threadIdx.x - off] : 0;
    __syncthreads();
    s[threadIdx.x] += t;
    __syncthreads();
  }
  if (gid < NN) srs[gid + 1] = s[threadIdx.x];
  if (threadIdx.x == 255) bsum[blockIdx.x] = s[255];
}
#define NB 391
__global__ __launch_bounds__(512) void scan_sums_kernel(int* __restrict__ bsum) {
  __shared__ int s[512];
  int tid = threadIdx.x;
  int v = (tid < NB) ? bsum[tid] : 0;
  s[tid] = v;
  __syncthreads();
  for (int off = 1; off < 512; off <<= 1) {
    int t = (tid >= off) ? s[tid - off] : 0;
    __syncthreads();
    s[tid] += t;
    __syncthreads();
  }
  if (tid < NB) bsum[tid] = (tid == 0) ? 0 : s[tid - 1];  // exclusive
}
__global__ __launch_bounds__(256) void add_off_kernel(int* __restrict__ srs,
                                                      const int* __restrict__ bsum) {
  int gid = blockIdx.x * 256 + threadIdx.x;
  if (gid < NN) srs[gid + 1] += bsum[blockIdx.x];
  if (gid == 0) srs[0] = 0;
}
__global__ __launch_bounds__(256) void scatter_kernel(
    const int* __restrict__ esrc, const int* __restrict__ edst,
    const float* __restrict__ eval, const int* __restrict__ srs,
    const int* __restrict__ spos, int* __restrict__ cursor,
    int2* __restrict__ csr_pair) {
  int e = blockIdx.x * 256 + threadIdx.x;
  if (e < NE) {
    int p = spos[edst[e]];
    int idx = srs[p] + atomicAdd(&cursor[p], 1);
    csr_pair[idx] = make_int2(esrc[e], __float_as_int(eval[e]));
  }
}

// ---------- propagation: zo[r] = 0.9 * (A z)[r] + 0.1 * h[r], bf16 ----------
__global__ __launch_bounds__(256) void prop_kernel(
    const int* __restrict__ srs, const int* __restrict__ perm,
    const int2* __restrict__ csr_pair, const unsigned short* __restrict__ zi,
    const unsigned short* __restrict__ hb, unsigned short* __restrict__ zo) {
  int t = blockIdx.x * 256 + threadIdx.x;
  if (t >= NN * 5) return;
  unsigned int p = (unsigned int)t / 5u;
  int cg8 = (t - (int)p * 5) * 8;  // col offset in bf16 elems
  int e0 = srs[p], e1 = srs[p + 1];
  int r = perm[p];
  float acc[8];
#pragma unroll
  for (int j = 0; j < 8; ++j) acc[j] = 0.f;

  int e = e0;
  for (; e + 8 <= e1; e += 8) {
    int2 pr[8];
#pragma unroll
    for (int q = 0; q < 8; ++q) pr[q] = csr_pair[e + q];
    uint4 g[8];
#pragma unroll
    for (int q = 0; q < 8; ++q)
      g[q] = *(const uint4*)(zi + pr[q].x * NCLS + cg8);
#pragma unroll
    for (int q = 0; q < 8; ++q) {
      float zf[8];
      bf8_to_f(g[q], zf);
      float v = __int_as_float(pr[q].y);
#pragma unroll
      for (int j = 0; j < 8; ++j) acc[j] = fmaf(v, zf[j], acc[j]);
    }
  }
  for (; e < e1; ++e) {
    int2 pr = csr_pair[e];
    uint4 g = *(const uint4*)(zi + pr.x * NCLS + cg8);
    float zf[8];
    bf8_to_f(g, zf);
    float v = __int_as_float(pr.y);
#pragma unroll
    for (int j = 0; j < 8; ++j) acc[j] = fmaf(v, zf[j], acc[j]);
  }

  uint4 hu = *(const uint4*)(hb + r * NCLS + cg8);
  float hf[8];
  bf8_to_f(hu, hf);
  uint4 o;
  unsigned int wv[4];
#pragma unroll
  for (int i = 0; i < 4; ++i) {
    unsigned int lo = f2bf(0.9f * acc[2 * i] + 0.1f * hf[2 * i]);
    unsigned int hi = f2bf(0.9f * acc[2 * i + 1] + 0.1f * hf[2 * i + 1]);
    wv[i] = lo | (hi << 16);
  }
  o.x = wv[0];
  o.y = wv[1];
  o.z = wv[2];
  o.w = wv[3];
  *(uint4*)(zo + r * NCLS + cg8) = o;
}

// ---------- log_softmax: bf16 z -> fp32 out ----------
__global__ __launch_bounds__(256) void lsm_kernel(const unsigned short* __restrict__ zf,
                                                  float* __restrict__ out) {
  int r = blockIdx.x * 256 + threadIdx.x;
  if (r >= NN) return;
  float v[NCLS];
#pragma unroll
  for (int q = 0; q < 5; ++q) {
    uint4 u = *(const uint4*)(zf + r * NCLS + q * 8);
    bf8_to_f(u, v + q * 8);
  }
  float m = v[0];
#pragma unroll
  for (int i = 1; i < NCLS; ++i) m = fmaxf(m, v[i]);
  float ssum = 0.f;
#pragma unroll
  for (int i = 0; i < NCLS; ++i) ssum += expf(v[i] - m);
  float lse = m + logf(ssum);
#pragma unroll
  for (int q = 0; q < 10; ++q) {
    float4 o;
    o.x = v[q * 4 + 0] - lse;
    o.y = v[q * 4 + 1] - lse;
    o.z = v[q * 4 + 2] - lse;
    o.w = v[q * 4 + 3] - lse;
    *(float4*)(out + r * NCLS + q * 4) = o;
  }
}

extern "C" void kernel_launch(void* const* d_in, const int* in_sizes, int n_in,
                              void* d_out, int out_size, void* d_ws, size_t ws_size,
                              hipStream_t stream) {
  const float* x = (const float*)d_in[0];
  const int* esrc = (const int*)d_in[1];
  const int* edst = (const int*)d_in[2];
  const float* eval = (const float*)d_in[3];
  const float* W1 = (const float*)d_in[4];
  const float* b1 = (const float*)d_in[5];
  const float* W2 = (const float*)d_in[6];
  const float* b2 = (const float*)d_in[7];
  float* out = (float*)d_out;
  char* ws = (char*)d_ws;

  // workspace layout (bytes), ~90.4 MB total
  unsigned short* hb = (unsigned short*)(ws + 0);         // 8,000,000 (h bf16)
  unsigned short* zB0 = (unsigned short*)(ws + 8000000);  // 8,000,000
  unsigned short* zB1 = (unsigned short*)(ws + 16000000); // 8,000,000
  unsigned short* Wt = (unsigned short*)(ws + 24000000);  // 262,144
  unsigned short* h1 = (unsigned short*)(ws + 24400000);  // 51,200,000
  int* counts = (int*)(ws + 75600000);                    // 400,000
  int* cursor = (int*)(ws + 76000000);                    // 400,000
  int* srs = (int*)(ws + 76400000);                       // 400,004 (+pad)
  int* bsum = (int*)(ws + 76800064);                      // 2,048
  int* binoff = (int*)(ws + 76802112);                    // 256
  int* perm = (int*)(ws + 76802624);                      // 400,000
  int* spos = (int*)(ws + 77202624);                      // 400,000
  int2* csr_pair = (int2*)(ws + 77602624);                // 12,800,000

  // zero counts + cursor (adjacent), and binoff
  zero_kernel<<<(2 * NN + 255) / 256, 256, 0, stream>>>(counts, 2 * NN);
  zero_kernel<<<1, 256, 0, stream>>>(binoff, 64);

  // MLP
  wt_kernel<<<(NFEATD * NHIDD) / 256, 256, 0, stream>>>(W1, Wt);
  gemm1_mfma_kernel<<<dim3(2, (NN + 127) / 128), 256, 0, stream>>>(x, Wt, b1, h1);
  gemm2_kernel<<<(NN + 63) / 64, 256, 0, stream>>>(h1, W2, b2, hb);

  // CSR build in degree-sorted row space
  count_kernel<<<(NE + 255) / 256, 256, 0, stream>>>(edst, counts);
  hist_kernel<<<(NN + 255) / 256, 256, 0, stream>>>(counts, binoff);
  binscan_kernel<<<1, 64, 0, stream>>>(binoff);
  scatter_rows_kernel<<<(NN + 255) / 256, 256, 0, stream>>>(counts, binoff, perm, spos);
  scan_blocks_kernel<<<NB, 256, 0, stream>>>(counts, perm, srs, bsum);
  scan_sums_kernel<<<1, 512, 0, stream>>>(bsum);
  add_off_kernel<<<NB, 256, 0, stream>>>(srs, bsum);
  scatter_kernel<<<(NE + 255) / 256, 256, 0, stream>>>(esrc, edst, eval, srs, spos,
                                                       cursor, csr_pair);

  // propagation: hb -> zB0 -> zB1 -> ... (10 hops, ends in zB1)
  const unsigned short* zin = hb;
  unsigned short* zout = zB0;
  for (int i = 0; i < KHOP; ++i) {
    prop_kernel<<<(NN * 5 + 255) / 256, 256, 0, stream>>>(srs, perm, csr_pair,
                                                          zin, hb, zout);
    if (i == 0) {
      zin = zB0;
      zout = zB1;
    } else {
      unsigned short* t = (unsigned short*)zin;
      zin = zout;
      zout = t;
    }
  }

  // log_softmax from bf16 z (hop 10 output = zB1) -> fp32 out
  lsm_kernel<<<(NN + 255) / 256, 256, 0, stream>>>(zB1, out);
}

// Round 4
// 1036.712 us; speedup vs baseline: 1.0674x; 1.0119x over previous
//
#include <hip/hip_runtime.h>
#include <hip/hip_bf16.h>
#include <math.h>

#define NN     100000
#define NFEATD 512
#define NHIDD  256
#define NCLS   40
#define NE     1600000
#define KHOP   10

typedef __attribute__((ext_vector_type(8))) short short8;
typedef __attribute__((ext_vector_type(4))) float floatx4;

// ---------- helpers ----------
static __device__ __forceinline__ float bf2f(unsigned int u) {
  unsigned int x = u << 16;
  float f;
  __builtin_memcpy(&f, &x, 4);
  return f;
}
static __device__ __forceinline__ unsigned short f2bf(float f) {
  unsigned int x;
  __builtin_memcpy(&x, &f, 4);
  x = (x + 0x7fffu + ((x >> 16) & 1u)) >> 16;
  return (unsigned short)x;
}
// 4 uints (8 packed bf16) -> 8 floats
static __device__ __forceinline__ void bf8_to_f(const uint4 u, float* f) {
  unsigned int a0 = u.x, a1 = u.y, a2 = u.z, a3 = u.w;
  unsigned int t;
  t = a0 << 16;          __builtin_memcpy(&f[0], &t, 4);
  t = a0 & 0xffff0000u;  __builtin_memcpy(&f[1], &t, 4);
  t = a1 << 16;          __builtin_memcpy(&f[2], &t, 4);
  t = a1 & 0xffff0000u;  __builtin_memcpy(&f[3], &t, 4);
  t = a2 << 16;          __builtin_memcpy(&f[4], &t, 4);
  t = a2 & 0xffff0000u;  __builtin_memcpy(&f[5], &t, 4);
  t = a3 << 16;          __builtin_memcpy(&f[6], &t, 4);
  t = a3 & 0xffff0000u;  __builtin_memcpy(&f[7], &t, 4);
}

// ---------- W1 [512][256] fp32 -> Wt [256][512] bf16 ----------
__global__ __launch_bounds__(256) void wt_kernel(const float* __restrict__ W1,
                                                 unsigned short* __restrict__ Wt) {
  int i = blockIdx.x * 256 + threadIdx.x;  // over 512*256
  int k = i >> 8;
  int n = i & 255;
  Wt[n * 512 + k] = f2bf(W1[i]);
}

// ---------- GEMM1: h1 = relu(x @ W1 + b1) ----------
// Round-3 schedule (1 barrier/K-step, lgkmcnt-only waits, full-line epilogue)
// with SINGLE-set register prefetch (24 regs, not 48) -> no scratch spill.
// Per substep: STAGE(regs -> next buf); LOAD(regs, tile+2); COMPUTE(cur); BAR.
__global__ __launch_bounds__(256) void gemm1_mfma_kernel(
    const float* __restrict__ x, const unsigned short* __restrict__ Wt,
    const float* __restrict__ b1, unsigned short* __restrict__ h1) {
  __shared__ __align__(16) unsigned short smem_u[20480];  // 40KB: 2x(As+Bs); hs overlays
  unsigned short* As0 = smem_u;           // [128][40]
  unsigned short* Bs0 = smem_u + 5120;    // [128][40]
  unsigned short* As1 = smem_u + 10240;
  unsigned short* Bs1 = smem_u + 15360;
  unsigned short* hs = smem_u;            // [128][128] epilogue overlay (32KB)
  const int tid = threadIdx.x;
  const int lane = tid & 63;
  const int wave = tid >> 6;
  const int wr = wave >> 1, wc = wave & 1;
  const int m = lane & 15, quad = lane >> 4;
  const int c0 = blockIdx.x * 128;  // col block (0 or 128)
  const int r0 = blockIdx.y * 128;  // row block

  const int arow = tid >> 3;  // 0..31 (+rep*32)
  const int akq = tid & 7;    // float4 index within 32-k tile
  const int brow = tid >> 2;  // 0..63 (+rep*64)
  const int bkq = tid & 3;    // 16B chunk within 32-k tile

  floatx4 acc[4][4];
#pragma unroll
  for (int i = 0; i < 4; ++i)
#pragma unroll
    for (int j = 0; j < 4; ++j) acc[i][j] = (floatx4){0.f, 0.f, 0.f, 0.f};

  // source pointers (rows clamped; OOB rows produce garbage h-rows that are
  // masked at the global store)
  const float* asrc[4];
#pragma unroll
  for (int rep = 0; rep < 4; ++rep) {
    int grow = r0 + arow + rep * 32;
    asrc[rep] = x + (size_t)(grow < NN ? grow : 0) * NFEATD + akq * 4;
  }
  const unsigned short* bsrc[2];
#pragma unroll
  for (int rep = 0; rep < 2; ++rep)
    bsrc[rep] = Wt + (size_t)(c0 + brow + rep * 64) * NFEATD + bkq * 8;

#define LOAD_A(dst, koff)                                        \
  {                                                              \
    _Pragma("unroll") for (int rep = 0; rep < 4; ++rep)          \
        dst[rep] = *(const float4*)(asrc[rep] + (koff));         \
  }
#define LOAD_B(dst, koff)                                        \
  {                                                              \
    _Pragma("unroll") for (int rep = 0; rep < 2; ++rep)          \
        dst[rep] = *(const uint4*)(bsrc[rep] + (koff));          \
  }
#define STAGE(Ad, Bd, aregs, bregs)                              \
  {                                                              \
    _Pragma("unroll") for (int rep = 0; rep < 4; ++rep) {        \
      ushort4 o;                                                 \
      o.x = f2bf(aregs[rep].x);                                  \
      o.y = f2bf(aregs[rep].y);                                  \
      o.z = f2bf(aregs[rep].z);                                  \
      o.w = f2bf(aregs[rep].w);                                  \
      *(ushort4*)&Ad[(arow + rep * 32) * 40 + akq * 4] = o;      \
    }                                                            \
    _Pragma("unroll") for (int rep = 0; rep < 2; ++rep)          \
        *(uint4*)&Bd[(brow + rep * 64) * 40 + bkq * 8] = bregs[rep]; \
  }
#define COMPUTE(Asb, Bsb)                                        \
  {                                                              \
    short8 af[4], bfr[4];                                        \
    _Pragma("unroll") for (int i = 0; i < 4; ++i)                \
        af[i] = *(const short8*)&Asb[(wr * 64 + i * 16 + m) * 40 + quad * 8]; \
    _Pragma("unroll") for (int j = 0; j < 4; ++j)                \
        bfr[j] = *(const short8*)&Bsb[(wc * 64 + j * 16 + m) * 40 + quad * 8]; \
    _Pragma("unroll") for (int i = 0; i < 4; ++i)                \
        _Pragma("unroll") for (int j = 0; j < 4; ++j)            \
            acc[i][j] = __builtin_amdgcn_mfma_f32_16x16x32_bf16( \
                af[i], bfr[j], acc[i][j], 0, 0, 0);              \
  }
#define BAR()                                                    \
  {                                                              \
    asm volatile("s_waitcnt lgkmcnt(0)" ::: "memory");           \
    __builtin_amdgcn_s_barrier();                                \
  }

  float4 aA[4];
  uint4 bA[2];
  // prologue: tile0 -> regs -> buf0; regs <- tile1
  LOAD_A(aA, 0); LOAD_B(bA, 0);
  STAGE(As0, Bs0, aA, bA);
  LOAD_A(aA, 32); LOAD_B(bA, 32);
  BAR();

  // 8 iterations x 2 tiles; tile s computed from buf[s&1]; stage runs 1 tile
  // ahead from the single reg set; loads run 2 tiles ahead (in flight across
  // one barrier interval).
#pragma unroll 1
  for (int t = 0; t < 8; ++t) {
    const int kt = t * 64;
    // ---- substep 0: compute tile 2t (buf0); stage tile 2t+1 (regs->buf1) ----
    STAGE(As1, Bs1, aA, bA);
    if (t < 7) { LOAD_A(aA, kt + 64); LOAD_B(bA, kt + 64); }  // tile 2t+2
    COMPUTE(As0, Bs0);
    BAR();
    // ---- substep 1: compute tile 2t+1 (buf1); stage tile 2t+2 (regs->buf0) ----
    if (t < 7) {
      STAGE(As0, Bs0, aA, bA);
      LOAD_A(aA, kt + 96); LOAD_B(bA, kt + 96);  // tile 2t+3
    }
    COMPUTE(As1, Bs1);
    BAR();
  }

  // epilogue: bias+relu -> bf16 tile in LDS -> full-line coalesced h1 write
  float bias[4];
#pragma unroll
  for (int j = 0; j < 4; ++j) bias[j] = b1[c0 + wc * 64 + j * 16 + m];
#pragma unroll
  for (int i = 0; i < 4; ++i)
#pragma unroll
    for (int r = 0; r < 4; ++r) {
      int rl = wr * 64 + i * 16 + quad * 4 + r;
#pragma unroll
      for (int j = 0; j < 4; ++j)
        hs[rl * 128 + wc * 64 + j * 16 + m] =
            f2bf(fmaxf(acc[i][j][r] + bias[j], 0.f));
    }
  BAR();
#pragma unroll
  for (int rep = 0; rep < 8; ++rep) {
    int idx = rep * 256 + tid;  // 16B chunk id; 2048 chunks = 32KB
    int row = idx >> 4;         // 16 chunks per 256B tile row
    int grow = r0 + row;
    if (grow < NN) {
      uint4 v = *(const uint4*)&hs[idx * 8];
      *(uint4*)(h1 + (size_t)grow * NHIDD + c0 + (idx & 15) * 8) = v;
    }
  }
#undef LOAD_A
#undef LOAD_B
#undef STAGE
#undef COMPUTE
#undef BAR
}

// ---------- GEMM2: hb(bf16) = h1(bf16) @ W2 + b2 ----------
// float4 W2 staging; float2 W2 inner reads (11 vs 21 LDS ops per 2-k).
__global__ __launch_bounds__(256) void gemm2_kernel(
    const unsigned short* __restrict__ h1, const float* __restrict__ W2,
    const float* __restrict__ b2, unsigned short* __restrict__ hb) {
  __shared__ float w2s[NHIDD * NCLS];  // 40 KB
  __shared__ float b2s[NCLS];
  __shared__ unsigned short h1s[64 * 264];  // padded stride
  const int tid = threadIdx.x;
  const int r0 = blockIdx.x * 64;
#pragma unroll
  for (int i = 0; i < 10; ++i)
    ((float4*)w2s)[tid + i * 256] = ((const float4*)W2)[tid + i * 256];
  if (tid < NCLS) b2s[tid] = b2[tid];
#pragma unroll
  for (int q = 0; q < 8; ++q) {
    int l = tid + q * 256;
    int lr = l >> 5;
    int lc = (l & 31) << 3;
    int row = r0 + lr;
    uint4 v = make_uint4(0, 0, 0, 0);
    if (row < NN) v = *(const uint4*)(h1 + (size_t)row * NHIDD + lc);
    *(uint4*)&h1s[lr * 264 + lc] = v;
  }
  __syncthreads();
  const int lr = tid >> 2;
  const int cq = (tid & 3) * 10;
  float acc[10];
#pragma unroll
  for (int j = 0; j < 10; ++j) acc[j] = 0.f;
#pragma unroll 4
  for (int k = 0; k < NHIDD; k += 2) {
    unsigned int hp = *(const unsigned int*)&h1s[lr * 264 + k];
    float a0 = bf2f(hp & 0xffffu);
    float a1 = bf2f(hp >> 16);
    const float* w0 = &w2s[k * NCLS + cq];
    const float* w1 = &w2s[(k + 1) * NCLS + cq];
#pragma unroll
    for (int j2 = 0; j2 < 5; ++j2) {
      float2 wa = *(const float2*)(w0 + 2 * j2);
      float2 wb = *(const float2*)(w1 + 2 * j2);
      acc[2 * j2] = fmaf(a1, wb.x, fmaf(a0, wa.x, acc[2 * j2]));
      acc[2 * j2 + 1] = fmaf(a1, wb.y, fmaf(a0, wa.y, acc[2 * j2 + 1]));
    }
  }
  int row = r0 + lr;
  if (row < NN) {
#pragma unroll
    for (int jj = 0; jj < 5; ++jj) {
      unsigned int u = (unsigned int)f2bf(acc[2 * jj] + b2s[cq + 2 * jj]) |
                       ((unsigned int)f2bf(acc[2 * jj + 1] + b2s[cq + 2 * jj + 1]) << 16);
      *(unsigned int*)&hb[(size_t)row * NCLS + cq + 2 * jj] = u;
    }
  }
}

// ---------- CSR build (degree-sorted row order, block-aggregated sort) ----------
__global__ __launch_bounds__(256) void zero_kernel(int* __restrict__ p, int n) {
  int i = blockIdx.x * 256 + threadIdx.x;
  if (i < n) p[i] = 0;
}
__global__ __launch_bounds__(256) void count_kernel(const int* __restrict__ edst,
                                                    int* __restrict__ counts) {
  int e = blockIdx.x * 256 + threadIdx.x;
  if (e < NE) atomicAdd(&counts[edst[e]], 1);
}
// block-local LDS histogram, one global atomic per (block, bin)
__global__ __launch_bounds__(256) void hist_kernel(const int* __restrict__ counts,
                                                   int* __restrict__ binoff) {
  __shared__ int lhist[64];
  int tid = threadIdx.x;
  if (tid < 64) lhist[tid] = 0;
  __syncthreads();
  int r = blockIdx.x * 256 + tid;
  if (r < NN) {
    int d = counts[r];
    if (d > 63) d = 63;
    atomicAdd(&lhist[d], 1);
  }
  __syncthreads();
  if (tid < 64) {
    int c = lhist[tid];
    if (c) atomicAdd(&binoff[tid], c);
  }
}
__global__ __launch_bounds__(64) void binscan_kernel(int* __restrict__ binoff) {
  __shared__ int s[64];
  int t = threadIdx.x;
  s[t] = binoff[t];
  __syncthreads();
  if (t == 0) {
    int run = 0;
    for (int i = 0; i < 64; ++i) {
      int c = s[i];
      s[i] = run;
      run += c;
    }
  }
  __syncthreads();
  binoff[t] = s[t];
}
// local rank via LDS atomics; block reserves a bin range with ONE global atomic
__global__ __launch_bounds__(256) void scatter_rows_kernel(
    const int* __restrict__ counts, int* __restrict__ binoff,
    int* __restrict__ perm, int* __restrict__ spos) {
  __shared__ int lhist[64];
  __shared__ int lbase[64];
  int tid = threadIdx.x;
  if (tid < 64) lhist[tid] = 0;
  __syncthreads();
  int r = blockIdx.x * 256 + tid;
  int d = 0, lrank = 0;
  bool valid = (r < NN);
  if (valid) {
    d = counts[r];
    if (d > 63) d = 63;
    lrank = atomicAdd(&lhist[d], 1);
  }
  __syncthreads();
  if (tid < 64) {
    int c = lhist[tid];
    lbase[tid] = c ? atomicAdd(&binoff[tid], c) : 0;
  }
  __syncthreads();
  if (valid) {
    int pos = lbase[d] + lrank;
    perm[pos] = r;
    spos[r] = pos;
  }
}
__global__ __launch_bounds__(256) void scan_blocks_kernel(
    const int* __restrict__ counts, const int* __restrict__ perm,
    int* __restrict__ srs, int* __restrict__ bsum) {
  __shared__ int s[256];
  int gid = blockIdx.x * 256 + threadIdx.x;
  int v = (gid < NN) ? counts[perm[gid]] : 0;
  s[threadIdx.x] = v;
  __syncthreads();
  for (int off = 1; off < 256; off <<= 1) {
    int t = (threadIdx.x >= off) ? s[threadIdx.x - off] : 0;
    __syncthreads();
    s[threadIdx.x] += t;
    __syncthreads();
  }
  if (gid < NN) srs[gid + 1] = s[threadIdx.x];
  if (threadIdx.x == 255) bsum[blockIdx.x] = s[255];
}
#define NB 391
__global__ __launch_bounds__(512) void scan_sums_kernel(int* __restrict__ bsum) {
  __shared__ int s[512];
  int tid = threadIdx.x;
  int v = (tid < NB) ? bsum[tid] : 0;
  s[tid] = v;
  __syncthreads();
  for (int off = 1; off < 512; off <<= 1) {
    int t = (tid >= off) ? s[tid - off] : 0;
    __syncthreads();
    s[tid] += t;
    __syncthreads();
  }
  if (tid < NB) bsum[tid] = (tid == 0) ? 0 : s[tid - 1];  // exclusive
}
__global__ __launch_bounds__(256) void add_off_kernel(int* __restrict__ srs,
                                                      const int* __restrict__ bsum) {
  int gid = blockIdx.x * 256 + threadIdx.x;
  if (gid < NN) srs[gid + 1] += bsum[blockIdx.x];
  if (gid == 0) srs[0] = 0;
}
__global__ __launch_bounds__(256) void scatter_kernel(
    const int* __restrict__ esrc, const int* __restrict__ edst,
    const float* __restrict__ eval, const int* __restrict__ srs,
    const int* __restrict__ spos, int* __restrict__ cursor,
    int2* __restrict__ csr_pair) {
  int e = blockIdx.x * 256 + threadIdx.x;
  if (e < NE) {
    int p = spos[edst[e]];
    int idx = srs[p] + atomicAdd(&cursor[p], 1);
    csr_pair[idx] = make_int2(esrc[e], __float_as_int(eval[e]));
  }
}

// ---------- propagation: zo[r] = 0.9 * (A z)[r] + 0.1 * h[r], bf16 ----------
__global__ __launch_bounds__(256) void prop_kernel(
    const int* __restrict__ srs, const int* __restrict__ perm,
    const int2* __restrict__ csr_pair, const unsigned short* __restrict__ zi,
    const unsigned short* __restrict__ hb, unsigned short* __restrict__ zo) {
  int t = blockIdx.x * 256 + threadIdx.x;
  if (t >= NN * 5) return;
  unsigned int p = (unsigned int)t / 5u;
  int cg8 = (t - (int)p * 5) * 8;  // col offset in bf16 elems
  int e0 = srs[p], e1 = srs[p + 1];
  int r = perm[p];
  float acc[8];
#pragma unroll
  for (int j = 0; j < 8; ++j) acc[j] = 0.f;

  int e = e0;
  for (; e + 8 <= e1; e += 8) {
    int2 pr[8];
#pragma unroll
    for (int q = 0; q < 8; ++q) pr[q] = csr_pair[e + q];
    uint4 g[8];
#pragma unroll
    for (int q = 0; q < 8; ++q)
      g[q] = *(const uint4*)(zi + pr[q].x * NCLS + cg8);
#pragma unroll
    for (int q = 0; q < 8; ++q) {
      float zf[8];
      bf8_to_f(g[q], zf);
      float v = __int_as_float(pr[q].y);
#pragma unroll
      for (int j = 0; j < 8; ++j) acc[j] = fmaf(v, zf[j], acc[j]);
    }
  }
  for (; e < e1; ++e) {
    int2 pr = csr_pair[e];
    uint4 g = *(const uint4*)(zi + pr.x * NCLS + cg8);
    float zf[8];
    bf8_to_f(g, zf);
    float v = __int_as_float(pr.y);
#pragma unroll
    for (int j = 0; j < 8; ++j) acc[j] = fmaf(v, zf[j], acc[j]);
  }

  uint4 hu = *(const uint4*)(hb + r * NCLS + cg8);
  float hf[8];
  bf8_to_f(hu, hf);
  uint4 o;
  unsigned int wv[4];
#pragma unroll
  for (int i = 0; i < 4; ++i) {
    unsigned int lo = f2bf(0.9f * acc[2 * i] + 0.1f * hf[2 * i]);
    unsigned int hi = f2bf(0.9f * acc[2 * i + 1] + 0.1f * hf[2 * i + 1]);
    wv[i] = lo | (hi << 16);
  }
  o.x = wv[0];
  o.y = wv[1];
  o.z = wv[2];
  o.w = wv[3];
  *(uint4*)(zo + r * NCLS + cg8) = o;
}

// ---------- log_softmax: bf16 z -> fp32 out ----------
__global__ __launch_bounds__(256) void lsm_kernel(const unsigned short* __restrict__ zf,
                                                  float* __restrict__ out) {
  int r = blockIdx.x * 256 + threadIdx.x;
  if (r >= NN) return;
  float v[NCLS];
#pragma unroll
  for (int q = 0; q < 5; ++q) {
    uint4 u = *(const uint4*)(zf + r * NCLS + q * 8);
    bf8_to_f(u, v + q * 8);
  }
  float m = v[0];
#pragma unroll
  for (int i = 1; i < NCLS; ++i) m = fmaxf(m, v[i]);
  float ssum = 0.f;
#pragma unroll
  for (int i = 0; i < NCLS; ++i) ssum += expf(v[i] - m);
  float lse = m + logf(ssum);
#pragma unroll
  for (int q = 0; q < 10; ++q) {
    float4 o;
    o.x = v[q * 4 + 0] - lse;
    o.y = v[q * 4 + 1] - lse;
    o.z = v[q * 4 + 2] - lse;
    o.w = v[q * 4 + 3] - lse;
    *(float4*)(out + r * NCLS + q * 4) = o;
  }
}

extern "C" void kernel_launch(void* const* d_in, const int* in_sizes, int n_in,
                              void* d_out, int out_size, void* d_ws, size_t ws_size,
                              hipStream_t stream) {
  const float* x = (const float*)d_in[0];
  const int* esrc = (const int*)d_in[1];
  const int* edst = (const int*)d_in[2];
  const float* eval = (const float*)d_in[3];
  const float* W1 = (const float*)d_in[4];
  const float* b1 = (const float*)d_in[5];
  const float* W2 = (const float*)d_in[6];
  const float* b2 = (const float*)d_in[7];
  float* out = (float*)d_out;
  char* ws = (char*)d_ws;

  // workspace layout (bytes), ~90.4 MB total
  unsigned short* hb = (unsigned short*)(ws + 0);         // 8,000,000 (h bf16)
  unsigned short* zB0 = (unsigned short*)(ws + 8000000);  // 8,000,000
  unsigned short* zB1 = (unsigned short*)(ws + 16000000); // 8,000,000
  unsigned short* Wt = (unsigned short*)(ws + 24000000);  // 262,144
  unsigned short* h1 = (unsigned short*)(ws + 24400000);  // 51,200,000
  int* counts = (int*)(ws + 75600000);                    // 400,000
  int* cursor = (int*)(ws + 76000000);                    // 400,000
  int* srs = (int*)(ws + 76400000);                       // 400,004 (+pad)
  int* bsum = (int*)(ws + 76800064);                      // 2,048
  int* binoff = (int*)(ws + 76802112);                    // 256
  int* perm = (int*)(ws + 76802624);                      // 400,000
  int* spos = (int*)(ws + 77202624);                      // 400,000
  int2* csr_pair = (int2*)(ws + 77602624);                // 12,800,000

  // zero counts + cursor (adjacent), and binoff
  zero_kernel<<<(2 * NN + 255) / 256, 256, 0, stream>>>(counts, 2 * NN);
  zero_kernel<<<1, 256, 0, stream>>>(binoff, 64);

  // MLP
  wt_kernel<<<(NFEATD * NHIDD) / 256, 256, 0, stream>>>(W1, Wt);
  gemm1_mfma_kernel<<<dim3(2, (NN + 127) / 128), 256, 0, stream>>>(x, Wt, b1, h1);
  gemm2_kernel<<<(NN + 63) / 64, 256, 0, stream>>>(h1, W2, b2, hb);

  // CSR build in degree-sorted row space
  count_kernel<<<(NE + 255) / 256, 256, 0, stream>>>(edst, counts);
  hist_kernel<<<(NN + 255) / 256, 256, 0, stream>>>(counts, binoff);
  binscan_kernel<<<1, 64, 0, stream>>>(binoff);
  scatter_rows_kernel<<<(NN + 255) / 256, 256, 0, stream>>>(counts, binoff, perm, spos);
  scan_blocks_kernel<<<NB, 256, 0, stream>>>(counts, perm, srs, bsum);
  scan_sums_kernel<<<1, 512, 0, stream>>>(bsum);
  add_off_kernel<<<NB, 256, 0, stream>>>(srs, bsum);
  scatter_kernel<<<(NE + 255) / 256, 256, 0, stream>>>(esrc, edst, eval, srs, spos,
                                                       cursor, csr_pair);

  // propagation: hb -> zB0 -> zB1 -> ... (10 hops, ends in zB1)
  const unsigned short* zin = hb;
  unsigned short* zout = zB0;
  for (int i = 0; i < KHOP; ++i) {
    prop_kernel<<<(NN * 5 + 255) / 256, 256, 0, stream>>>(srs, perm, csr_pair,
                                                          zin, hb, zout);
    if (i == 0) {
      zin = zB0;
      zout = zB1;
    } else {
      unsigned short* t = (unsigned short*)zin;
      zin = zout;
      zout = t;
    }
  }

  // log_softmax from bf16 z (hop 10 output = zB1) -> fp32 out
  lsm_kernel<<<(NN + 255) / 256, 256, 0, stream>>>(zB1, out);
}

// Round 5
// 960.840 us; speedup vs baseline: 1.1517x; 1.0790x over previous
//
#include <hip/hip_runtime.h>
#include <hip/hip_bf16.h>
#include <math.h>

#define NN     100000
#define NFEATD 512
#define NHIDD  256
#define NCLS   40
#define NE     1600000
#define KHOP   10

typedef __attribute__((ext_vector_type(8))) short short8;
typedef __attribute__((ext_vector_type(4))) float floatx4;

// ---------- helpers ----------
static __device__ __forceinline__ float bf2f(unsigned int u) {
  unsigned int x = u << 16;
  float f;
  __builtin_memcpy(&f, &x, 4);
  return f;
}
static __device__ __forceinline__ unsigned short f2bf(float f) {
  unsigned int x;
  __builtin_memcpy(&x, &f, 4);
  x = (x + 0x7fffu + ((x >> 16) & 1u)) >> 16;
  return (unsigned short)x;
}
// 4 uints (8 packed bf16) -> 8 floats
static __device__ __forceinline__ void bf8_to_f(const uint4 u, float* f) {
  unsigned int a0 = u.x, a1 = u.y, a2 = u.z, a3 = u.w;
  unsigned int t;
  t = a0 << 16;          __builtin_memcpy(&f[0], &t, 4);
  t = a0 & 0xffff0000u;  __builtin_memcpy(&f[1], &t, 4);
  t = a1 << 16;          __builtin_memcpy(&f[2], &t, 4);
  t = a1 & 0xffff0000u;  __builtin_memcpy(&f[3], &t, 4);
  t = a2 << 16;          __builtin_memcpy(&f[4], &t, 4);
  t = a2 & 0xffff0000u;  __builtin_memcpy(&f[5], &t, 4);
  t = a3 << 16;          __builtin_memcpy(&f[6], &t, 4);
  t = a3 & 0xffff0000u;  __builtin_memcpy(&f[7], &t, 4);
}

// ---------- W1 [512][256] fp32 -> Wt [256][512] bf16 ----------
__global__ __launch_bounds__(256) void wt_kernel(const float* __restrict__ W1,
                                                 unsigned short* __restrict__ Wt) {
  int i = blockIdx.x * 256 + threadIdx.x;  // over 512*256
  int k = i >> 8;
  int n = i & 255;
  Wt[n * 512 + k] = f2bf(W1[i]);
}

// ---------- GEMM1: h1 = relu(x @ W1 + b1) ----------
// (unchanged from round 4)
__global__ __launch_bounds__(256) void gemm1_mfma_kernel(
    const float* __restrict__ x, const unsigned short* __restrict__ Wt,
    const float* __restrict__ b1, unsigned short* __restrict__ h1) {
  __shared__ __align__(16) unsigned short smem_u[20480];  // 40KB: 2x(As+Bs); hs overlays
  unsigned short* As0 = smem_u;           // [128][40]
  unsigned short* Bs0 = smem_u + 5120;    // [128][40]
  unsigned short* As1 = smem_u + 10240;
  unsigned short* Bs1 = smem_u + 15360;
  unsigned short* hs = smem_u;            // [128][128] epilogue overlay (32KB)
  const int tid = threadIdx.x;
  const int lane = tid & 63;
  const int wave = tid >> 6;
  const int wr = wave >> 1, wc = wave & 1;
  const int m = lane & 15, quad = lane >> 4;
  const int c0 = blockIdx.x * 128;  // col block (0 or 128)
  const int r0 = blockIdx.y * 128;  // row block

  const int arow = tid >> 3;  // 0..31 (+rep*32)
  const int akq = tid & 7;    // float4 index within 32-k tile
  const int brow = tid >> 2;  // 0..63 (+rep*64)
  const int bkq = tid & 3;    // 16B chunk within 32-k tile

  floatx4 acc[4][4];
#pragma unroll
  for (int i = 0; i < 4; ++i)
#pragma unroll
    for (int j = 0; j < 4; ++j) acc[i][j] = (floatx4){0.f, 0.f, 0.f, 0.f};

  const float* asrc[4];
#pragma unroll
  for (int rep = 0; rep < 4; ++rep) {
    int grow = r0 + arow + rep * 32;
    asrc[rep] = x + (size_t)(grow < NN ? grow : 0) * NFEATD + akq * 4;
  }
  const unsigned short* bsrc[2];
#pragma unroll
  for (int rep = 0; rep < 2; ++rep)
    bsrc[rep] = Wt + (size_t)(c0 + brow + rep * 64) * NFEATD + bkq * 8;

#define LOAD_A(dst, koff)                                        \
  {                                                              \
    _Pragma("unroll") for (int rep = 0; rep < 4; ++rep)          \
        dst[rep] = *(const float4*)(asrc[rep] + (koff));         \
  }
#define LOAD_B(dst, koff)                                        \
  {                                                              \
    _Pragma("unroll") for (int rep = 0; rep < 2; ++rep)          \
        dst[rep] = *(const uint4*)(bsrc[rep] + (koff));          \
  }
#define STAGE(Ad, Bd, aregs, bregs)                              \
  {                                                              \
    _Pragma("unroll") for (int rep = 0; rep < 4; ++rep) {        \
      ushort4 o;                                                 \
      o.x = f2bf(aregs[rep].x);                                  \
      o.y = f2bf(aregs[rep].y);                                  \
      o.z = f2bf(aregs[rep].z);                                  \
      o.w = f2bf(aregs[rep].w);                                  \
      *(ushort4*)&Ad[(arow + rep * 32) * 40 + akq * 4] = o;      \
    }                                                            \
    _Pragma("unroll") for (int rep = 0; rep < 2; ++rep)          \
        *(uint4*)&Bd[(brow + rep * 64) * 40 + bkq * 8] = bregs[rep]; \
  }
#define COMPUTE(Asb, Bsb)                                        \
  {                                                              \
    short8 af[4], bfr[4];                                        \
    _Pragma("unroll") for (int i = 0; i < 4; ++i)                \
        af[i] = *(const short8*)&Asb[(wr * 64 + i * 16 + m) * 40 + quad * 8]; \
    _Pragma("unroll") for (int j = 0; j < 4; ++j)                \
        bfr[j] = *(const short8*)&Bsb[(wc * 64 + j * 16 + m) * 40 + quad * 8]; \
    _Pragma("unroll") for (int i = 0; i < 4; ++i)                \
        _Pragma("unroll") for (int j = 0; j < 4; ++j)            \
            acc[i][j] = __builtin_amdgcn_mfma_f32_16x16x32_bf16( \
                af[i], bfr[j], acc[i][j], 0, 0, 0);              \
  }
#define BAR()                                                    \
  {                                                              \
    asm volatile("s_waitcnt lgkmcnt(0)" ::: "memory");           \
    __builtin_amdgcn_s_barrier();                                \
  }

  float4 aA[4];
  uint4 bA[2];
  // prologue: tile0 -> regs -> buf0; regs <- tile1
  LOAD_A(aA, 0); LOAD_B(bA, 0);
  STAGE(As0, Bs0, aA, bA);
  LOAD_A(aA, 32); LOAD_B(bA, 32);
  BAR();

#pragma unroll 1
  for (int t = 0; t < 8; ++t) {
    const int kt = t * 64;
    // ---- substep 0: compute tile 2t (buf0); stage tile 2t+1 (regs->buf1) ----
    STAGE(As1, Bs1, aA, bA);
    if (t < 7) { LOAD_A(aA, kt + 64); LOAD_B(bA, kt + 64); }  // tile 2t+2
    COMPUTE(As0, Bs0);
    BAR();
    // ---- substep 1: compute tile 2t+1 (buf1); stage tile 2t+2 (regs->buf0) ----
    if (t < 7) {
      STAGE(As0, Bs0, aA, bA);
      LOAD_A(aA, kt + 96); LOAD_B(bA, kt + 96);  // tile 2t+3
    }
    COMPUTE(As1, Bs1);
    BAR();
  }

  // epilogue: bias+relu -> bf16 tile in LDS -> full-line coalesced h1 write
  float bias[4];
#pragma unroll
  for (int j = 0; j < 4; ++j) bias[j] = b1[c0 + wc * 64 + j * 16 + m];
#pragma unroll
  for (int i = 0; i < 4; ++i)
#pragma unroll
    for (int r = 0; r < 4; ++r) {
      int rl = wr * 64 + i * 16 + quad * 4 + r;
#pragma unroll
      for (int j = 0; j < 4; ++j)
        hs[rl * 128 + wc * 64 + j * 16 + m] =
            f2bf(fmaxf(acc[i][j][r] + bias[j], 0.f));
    }
  BAR();
#pragma unroll
  for (int rep = 0; rep < 8; ++rep) {
    int idx = rep * 256 + tid;  // 16B chunk id; 2048 chunks = 32KB
    int row = idx >> 4;         // 16 chunks per 256B tile row
    int grow = r0 + row;
    if (grow < NN) {
      uint4 v = *(const uint4*)&hs[idx * 8];
      *(uint4*)(h1 + (size_t)grow * NHIDD + c0 + (idx & 15) * 8) = v;
    }
  }
#undef LOAD_A
#undef LOAD_B
#undef STAGE
#undef COMPUTE
#undef BAR
}

// ---------- GEMM2: hb(bf16) = h1(bf16) @ W2 + b2 ----------
// (unchanged from round 4)
__global__ __launch_bounds__(256) void gemm2_kernel(
    const unsigned short* __restrict__ h1, const float* __restrict__ W2,
    const float* __restrict__ b2, unsigned short* __restrict__ hb) {
  __shared__ float w2s[NHIDD * NCLS];  // 40 KB
  __shared__ float b2s[NCLS];
  __shared__ unsigned short h1s[64 * 264];  // padded stride
  const int tid = threadIdx.x;
  const int r0 = blockIdx.x * 64;
#pragma unroll
  for (int i = 0; i < 10; ++i)
    ((float4*)w2s)[tid + i * 256] = ((const float4*)W2)[tid + i * 256];
  if (tid < NCLS) b2s[tid] = b2[tid];
#pragma unroll
  for (int q = 0; q < 8; ++q) {
    int l = tid + q * 256;
    int lr = l >> 5;
    int lc = (l & 31) << 3;
    int row = r0 + lr;
    uint4 v = make_uint4(0, 0, 0, 0);
    if (row < NN) v = *(const uint4*)(h1 + (size_t)row * NHIDD + lc);
    *(uint4*)&h1s[lr * 264 + lc] = v;
  }
  __syncthreads();
  const int lr = tid >> 2;
  const int cq = (tid & 3) * 10;
  float acc[10];
#pragma unroll
  for (int j = 0; j < 10; ++j) acc[j] = 0.f;
#pragma unroll 4
  for (int k = 0; k < NHIDD; k += 2) {
    unsigned int hp = *(const unsigned int*)&h1s[lr * 264 + k];
    float a0 = bf2f(hp & 0xffffu);
    float a1 = bf2f(hp >> 16);
    const float* w0 = &w2s[k * NCLS + cq];
    const float* w1 = &w2s[(k + 1) * NCLS + cq];
#pragma unroll
    for (int j2 = 0; j2 < 5; ++j2) {
      float2 wa = *(const float2*)(w0 + 2 * j2);
      float2 wb = *(const float2*)(w1 + 2 * j2);
      acc[2 * j2] = fmaf(a1, wb.x, fmaf(a0, wa.x, acc[2 * j2]));
      acc[2 * j2 + 1] = fmaf(a1, wb.y, fmaf(a0, wa.y, acc[2 * j2 + 1]));
    }
  }
  int row = r0 + lr;
  if (row < NN) {
#pragma unroll
    for (int jj = 0; jj < 5; ++jj) {
      unsigned int u = (unsigned int)f2bf(acc[2 * jj] + b2s[cq + 2 * jj]) |
                       ((unsigned int)f2bf(acc[2 * jj + 1] + b2s[cq + 2 * jj + 1]) << 16);
      *(unsigned int*)&hb[(size_t)row * NCLS + cq + 2 * jj] = u;
    }
  }
}

// ---------- CSR build (degree-sorted row order, block-aggregated sort) ----------
__global__ __launch_bounds__(256) void zero_kernel(int* __restrict__ p, int n) {
  int i = blockIdx.x * 256 + threadIdx.x;
  if (i < n) p[i] = 0;
}
__global__ __launch_bounds__(256) void count_kernel(const int* __restrict__ edst,
                                                    int* __restrict__ counts) {
  int e = blockIdx.x * 256 + threadIdx.x;
  if (e < NE) atomicAdd(&counts[edst[e]], 1);
}
// block-local LDS histogram, one global atomic per (block, bin)
__global__ __launch_bounds__(256) void hist_kernel(const int* __restrict__ counts,
                                                   int* __restrict__ binoff) {
  __shared__ int lhist[64];
  int tid = threadIdx.x;
  if (tid < 64) lhist[tid] = 0;
  __syncthreads();
  int r = blockIdx.x * 256 + tid;
  if (r < NN) {
    int d = counts[r];
    if (d > 63) d = 63;
    atomicAdd(&lhist[d], 1);
  }
  __syncthreads();
  if (tid < 64) {
    int c = lhist[tid];
    if (c) atomicAdd(&binoff[tid], c);
  }
}
__global__ __launch_bounds__(64) void binscan_kernel(int* __restrict__ binoff) {
  __shared__ int s[64];
  int t = threadIdx.x;
  s[t] = binoff[t];
  __syncthreads();
  if (t == 0) {
    int run = 0;
    for (int i = 0; i < 64; ++i) {
      int c = s[i];
      s[i] = run;
      run += c;
    }
  }
  __syncthreads();
  binoff[t] = s[t];
}
// local rank via LDS atomics; block reserves a bin range with ONE global atomic
__global__ __launch_bounds__(256) void scatter_rows_kernel(
    const int* __restrict__ counts, int* __restrict__ binoff,
    int* __restrict__ perm, int* __restrict__ spos) {
  __shared__ int lhist[64];
  __shared__ int lbase[64];
  int tid = threadIdx.x;
  if (tid < 64) lhist[tid] = 0;
  __syncthreads();
  int r = blockIdx.x * 256 + tid;
  int d = 0, lrank = 0;
  bool valid = (r < NN);
  if (valid) {
    d = counts[r];
    if (d > 63) d = 63;
    lrank = atomicAdd(&lhist[d], 1);
  }
  __syncthreads();
  if (tid < 64) {
    int c = lhist[tid];
    lbase[tid] = c ? atomicAdd(&binoff[tid], c) : 0;
  }
  __syncthreads();
  if (valid) {
    int pos = lbase[d] + lrank;
    perm[pos] = r;
    spos[r] = pos;
  }
}
__global__ __launch_bounds__(256) void scan_blocks_kernel(
    const int* __restrict__ counts, const int* __restrict__ perm,
    int* __restrict__ srs, int* __restrict__ bsum) {
  __shared__ int s[256];
  int gid = blockIdx.x * 256 + threadIdx.x;
  int v = (gid < NN) ? counts[perm[gid]] : 0;
  s[threadIdx.x] = v;
  __syncthreads();
  for (int off = 1; off < 256; off <<= 1) {
    int t = (threadIdx.x >= off) ? s[threadIdx.x - off] : 0;
    __syncthreads();
    s[threadIdx.x] += t;
    __syncthreads();
  }
  if (gid < NN) srs[gid + 1] = s[threadIdx.x];
  if (threadIdx.x == 255) bsum[blockIdx.x] = s[255];
}
#define NB 391
__global__ __launch_bounds__(512) void scan_sums_kernel(int* __restrict__ bsum) {
  __shared__ int s[512];
  int tid = threadIdx.x;
  int v = (tid < NB) ? bsum[tid] : 0;
  s[tid] = v;
  __syncthreads();
  for (int off = 1; off < 512; off <<= 1) {
    int t = (tid >= off) ? s[tid - off] : 0;
    __syncthreads();
    s[tid] += t;
    __syncthreads();
  }
  if (tid < NB) bsum[tid] = (tid == 0) ? 0 : s[tid - 1];  // exclusive
}
__global__ __launch_bounds__(256) void add_off_kernel(int* __restrict__ srs,
                                                      const int* __restrict__ bsum) {
  int gid = blockIdx.x * 256 + threadIdx.x;
  if (gid < NN) srs[gid + 1] += bsum[blockIdx.x];
  if (gid == 0) srs[0] = 0;
}
__global__ __launch_bounds__(256) void scatter_kernel(
    const int* __restrict__ esrc, const int* __restrict__ edst,
    const float* __restrict__ eval, const int* __restrict__ srs,
    const int* __restrict__ spos, int* __restrict__ cursor,
    int2* __restrict__ csr_pair) {
  int e = blockIdx.x * 256 + threadIdx.x;
  if (e < NE) {
    int p = spos[edst[e]];
    int idx = srs[p] + atomicAdd(&cursor[p], 1);
    csr_pair[idx] = make_int2(esrc[e], __float_as_int(eval[e]));
  }
}

// ---------- propagation v2: block-cooperative edge staging ----------
// zo[r] = 0.9 * (A z)[r] + 0.1 * h[r], bf16.
// Block owns 48 rows (wave = 12 rows x 5 col-groups; lanes 60-63 idle).
// The block's contiguous CSR edge range is staged ONCE into LDS with
// coalesced int2 loads (16KB chunks), replacing the 5x-redundant per-thread
// global pair reads (~1/3 of the kernel's L2 line-transactions).
// Per-row accumulation order (ascending e) is unchanged -> same numerics.
#define PROWS 48
#define ECHUNK 2048
__global__ __launch_bounds__(256) void prop_kernel(
    const int* __restrict__ srs, const int* __restrict__ perm,
    const int2* __restrict__ csr_pair, const unsigned short* __restrict__ zi,
    const unsigned short* __restrict__ hb, unsigned short* __restrict__ zo) {
  __shared__ int2 epairs[ECHUNK];  // 16 KB
  const int tid = threadIdx.x;
  const int lane = tid & 63;
  const int wave = tid >> 6;
  const int rw = lane / 5;          // row within wave (0..12); valid if lane<60
  const int g = lane - rw * 5;      // col group 0..4
  const int p_base = blockIdx.x * PROWS;
  const int p = p_base + wave * 12 + rw;
  const bool active = (lane < 60) && (rw < 12) && (p < NN);
  int pend = p_base + PROWS;
  if (pend > NN) pend = NN;
  const int eb = srs[p_base];
  const int ee = srs[pend];
  int e0 = 0, e1 = 0, r = 0;
  if (active) {
    e0 = srs[p];
    e1 = srs[p + 1];
    r = perm[p];
  }
  const int cg8 = g * 8;
  float acc[8];
#pragma unroll
  for (int j = 0; j < 8; ++j) acc[j] = 0.f;

  for (int cb = eb; cb < ee; cb += ECHUNK) {
    int cnt = ee - cb;
    if (cnt > ECHUNK) cnt = ECHUNK;
    __syncthreads();  // previous chunk fully consumed
    for (int i = tid; i < cnt; i += 256) epairs[i] = csr_pair[cb + i];
    __syncthreads();
    if (active) {
      int s = e0 > cb ? e0 : cb;
      int t_ = e1 < cb + cnt ? e1 : cb + cnt;
      int e = s;
      for (; e + 4 <= t_; e += 4) {
        int2 pr0 = epairs[e - cb];
        int2 pr1 = epairs[e - cb + 1];
        int2 pr2 = epairs[e - cb + 2];
        int2 pr3 = epairs[e - cb + 3];
        uint4 g0 = *(const uint4*)(zi + (size_t)pr0.x * NCLS + cg8);
        uint4 g1 = *(const uint4*)(zi + (size_t)pr1.x * NCLS + cg8);
        uint4 g2 = *(const uint4*)(zi + (size_t)pr2.x * NCLS + cg8);
        uint4 g3 = *(const uint4*)(zi + (size_t)pr3.x * NCLS + cg8);
        float zf[8];
        bf8_to_f(g0, zf);
        float v0 = __int_as_float(pr0.y);
#pragma unroll
        for (int j = 0; j < 8; ++j) acc[j] = fmaf(v0, zf[j], acc[j]);
        bf8_to_f(g1, zf);
        float v1 = __int_as_float(pr1.y);
#pragma unroll
        for (int j = 0; j < 8; ++j) acc[j] = fmaf(v1, zf[j], acc[j]);
        bf8_to_f(g2, zf);
        float v2 = __int_as_float(pr2.y);
#pragma unroll
        for (int j = 0; j < 8; ++j) acc[j] = fmaf(v2, zf[j], acc[j]);
        bf8_to_f(g3, zf);
        float v3 = __int_as_float(pr3.y);
#pragma unroll
        for (int j = 0; j < 8; ++j) acc[j] = fmaf(v3, zf[j], acc[j]);
      }
      for (; e < t_; ++e) {
        int2 pr = epairs[e - cb];
        uint4 gq = *(const uint4*)(zi + (size_t)pr.x * NCLS + cg8);
        float zf[8];
        bf8_to_f(gq, zf);
        float v = __int_as_float(pr.y);
#pragma unroll
        for (int j = 0; j < 8; ++j) acc[j] = fmaf(v, zf[j], acc[j]);
      }
    }
  }

  if (active) {
    uint4 hu = *(const uint4*)(hb + (size_t)r * NCLS + cg8);
    float hf[8];
    bf8_to_f(hu, hf);
    uint4 o;
    unsigned int wv[4];
#pragma unroll
    for (int i = 0; i < 4; ++i) {
      unsigned int lo = f2bf(0.9f * acc[2 * i] + 0.1f * hf[2 * i]);
      unsigned int hi = f2bf(0.9f * acc[2 * i + 1] + 0.1f * hf[2 * i + 1]);
      wv[i] = lo | (hi << 16);
    }
    o.x = wv[0];
    o.y = wv[1];
    o.z = wv[2];
    o.w = wv[3];
    *(uint4*)(zo + (size_t)r * NCLS + cg8) = o;
  }
}

// ---------- log_softmax: bf16 z -> fp32 out ----------
__global__ __launch_bounds__(256) void lsm_kernel(const unsigned short* __restrict__ zf,
                                                  float* __restrict__ out) {
  int r = blockIdx.x * 256 + threadIdx.x;
  if (r >= NN) return;
  float v[NCLS];
#pragma unroll
  for (int q = 0; q < 5; ++q) {
    uint4 u = *(const uint4*)(zf + r * NCLS + q * 8);
    bf8_to_f(u, v + q * 8);
  }
  float m = v[0];
#pragma unroll
  for (int i = 1; i < NCLS; ++i) m = fmaxf(m, v[i]);
  float ssum = 0.f;
#pragma unroll
  for (int i = 0; i < NCLS; ++i) ssum += expf(v[i] - m);
  float lse = m + logf(ssum);
#pragma unroll
  for (int q = 0; q < 10; ++q) {
    float4 o;
    o.x = v[q * 4 + 0] - lse;
    o.y = v[q * 4 + 1] - lse;
    o.z = v[q * 4 + 2] - lse;
    o.w = v[q * 4 + 3] - lse;
    *(float4*)(out + r * NCLS + q * 4) = o;
  }
}

extern "C" void kernel_launch(void* const* d_in, const int* in_sizes, int n_in,
                              void* d_out, int out_size, void* d_ws, size_t ws_size,
                              hipStream_t stream) {
  const float* x = (const float*)d_in[0];
  const int* esrc = (const int*)d_in[1];
  const int* edst = (const int*)d_in[2];
  const float* eval = (const float*)d_in[3];
  const float* W1 = (const float*)d_in[4];
  const float* b1 = (const float*)d_in[5];
  const float* W2 = (const float*)d_in[6];
  const float* b2 = (const float*)d_in[7];
  float* out = (float*)d_out;
  char* ws = (char*)d_ws;

  // workspace layout (bytes), ~90.4 MB total
  unsigned short* hb = (unsigned short*)(ws + 0);         // 8,000,000 (h bf16)
  unsigned short* zB0 = (unsigned short*)(ws + 8000000);  // 8,000,000
  unsigned short* zB1 = (unsigned short*)(ws + 16000000); // 8,000,000
  unsigned short* Wt = (unsigned short*)(ws + 24000000);  // 262,144
  unsigned short* h1 = (unsigned short*)(ws + 24400000);  // 51,200,000
  int* counts = (int*)(ws + 75600000);                    // 400,000
  int* cursor = (int*)(ws + 76000000);                    // 400,000
  int* srs = (int*)(ws + 76400000);                       // 400,004 (+pad)
  int* bsum = (int*)(ws + 76800064);                      // 2,048
  int* binoff = (int*)(ws + 76802112);                    // 256
  int* perm = (int*)(ws + 76802624);                      // 400,000
  int* spos = (int*)(ws + 77202624);                      // 400,000
  int2* csr_pair = (int2*)(ws + 77602624);                // 12,800,000

  // zero counts + cursor (adjacent), and binoff
  zero_kernel<<<(2 * NN + 255) / 256, 256, 0, stream>>>(counts, 2 * NN);
  zero_kernel<<<1, 256, 0, stream>>>(binoff, 64);

  // MLP
  wt_kernel<<<(NFEATD * NHIDD) / 256, 256, 0, stream>>>(W1, Wt);
  gemm1_mfma_kernel<<<dim3(2, (NN + 127) / 128), 256, 0, stream>>>(x, Wt, b1, h1);
  gemm2_kernel<<<(NN + 63) / 64, 256, 0, stream>>>(h1, W2, b2, hb);

  // CSR build in degree-sorted row space
  count_kernel<<<(NE + 255) / 256, 256, 0, stream>>>(edst, counts);
  hist_kernel<<<(NN + 255) / 256, 256, 0, stream>>>(counts, binoff);
  binscan_kernel<<<1, 64, 0, stream>>>(binoff);
  scatter_rows_kernel<<<(NN + 255) / 256, 256, 0, stream>>>(counts, binoff, perm, spos);
  scan_blocks_kernel<<<NB, 256, 0, stream>>>(counts, perm, srs, bsum);
  scan_sums_kernel<<<1, 512, 0, stream>>>(bsum);
  add_off_kernel<<<NB, 256, 0, stream>>>(srs, bsum);
  scatter_kernel<<<(NE + 255) / 256, 256, 0, stream>>>(esrc, edst, eval, srs, spos,
                                                       cursor, csr_pair);

  // propagation: hb -> zB0 -> zB1 -> ... (10 hops, ends in zB1)
  const unsigned short* zin = hb;
  unsigned short* zout = zB0;
  for (int i = 0; i < KHOP; ++i) {
    prop_kernel<<<(NN + PROWS - 1) / PROWS, 256, 0, stream>>>(srs, perm, csr_pair,
                                                              zin, hb, zout);
    if (i == 0) {
      zin = zB0;
      zout = zB1;
    } else {
      unsigned short* t = (unsigned short*)zin;
      zin = zout;
      zout = t;
    }
  }

  // log_softmax from bf16 z (hop 10 output = zB1) -> fp32 out
  lsm_kernel<<<(NN + 255) / 256, 256, 0, stream>>>(zB1, out);
}